// Round 14
// baseline (318.010 us; speedup 1.0000x reference)
//
#include <hip/hip_runtime.h>
#include <math.h>

#define T_DIM 2048
#define B_DIM 16
#define H_DIM 512
#define NKB   (H_DIM / 32)   // 16 k-blocks of 32
// out: results [T,B,2H] (33,554,432 f32) then attn [B,T,T] (67,108,864 f32)
// ws (ushort = fp16 bits), arrays TILED: tile(rowblk,kblk) = 8KB as [g(4)][row(128)][8]
//   Xh @0 (32MB), Qh @32Mi elems (32MB), Wth @64Mi elems (512KB).
// Raw scores: fp16 packed into the LOW HALF of each attn row, overwritten by k_softmax.

typedef _Float16 f16x8 __attribute__((ext_vector_type(8)));
typedef float f32x4 __attribute__((ext_vector_type(4)));

__device__ __forceinline__ unsigned short h_bits(_Float16 h) {
    unsigned short u; __builtin_memcpy(&u, &h, 2); return u;
}
__device__ __forceinline__ float h2f(unsigned short u) {
    _Float16 h; __builtin_memcpy(&h, &u, 2); return (float)h;
}

__device__ __forceinline__ size_t tile_off(int rowblk, int kblk) {
    return ((size_t)rowblk * NKB + kblk) * 4096;   // 4096 ushorts = 8KB per tile
}
__device__ __forceinline__ size_t tiled_idx(int r, int c) {
    return tile_off(r >> 7, c >> 5) + (size_t)((c >> 3) & 3) * 1024 + (size_t)(r & 127) * 8 + (c & 7);
}

// ---------- Kernel 1: results copy + X -> fp16 (tiled) ; tail blocks: W transpose ----------
__global__ __launch_bounds__(256) void k_prep(const float* __restrict__ X,
                                              const float* __restrict__ RC,
                                              const float* __restrict__ W,
                                              float* __restrict__ out,
                                              unsigned short* __restrict__ Xh,
                                              unsigned short* __restrict__ Wth) {
    if (blockIdx.x >= 8192) {
        int i = (blockIdx.x - 8192) * 256 + threadIdx.x;
        int n = i & 511;
        int k0 = (i >> 9) * 8;
        unsigned int hw[4];
#pragma unroll
        for (int e = 0; e < 4; ++e) {
            _Float16 h0 = (_Float16)W[(size_t)(k0 + 2 * e) * H_DIM + n];
            _Float16 h1 = (_Float16)W[(size_t)(k0 + 2 * e + 1) * H_DIM + n];
            hw[e] = (unsigned int)h_bits(h0) | ((unsigned int)h_bits(h1) << 16);
        }
        *(uint4*)(Wth + tiled_idx(n, k0)) = make_uint4(hw[0], hw[1], hw[2], hw[3]);
        return;
    }
    int i = blockIdx.x * 256 + threadIdx.x;
    int row = i >> 6;                 // t*B + b
    int h0 = (i & 63) * 8;
    int t = row >> 4;
    int b = row & 15;
    const float* xp = X + (size_t)row * H_DIM + h0;
    float4 v0 = *(const float4*)xp;
    float4 v1 = *(const float4*)(xp + 4);
    float* op = out + (size_t)row * (2 * H_DIM) + h0;
    *(float4*)op = v0;
    *(float4*)(op + 4) = v1;
    const float* cp = RC + (size_t)row * H_DIM + h0;
    float4 c0 = *(const float4*)cp;
    float4 c1 = *(const float4*)(cp + 4);
    if (t < 2) { c0 = v0; c1 = v1; }
    *(float4*)(op + H_DIM) = c0;
    *(float4*)(op + H_DIM + 4) = c1;
    float xs[8] = {v0.x, v0.y, v0.z, v0.w, v1.x, v1.y, v1.z, v1.w};
    unsigned int hw[4];
#pragma unroll
    for (int e = 0; e < 4; ++e) {
        _Float16 a = (_Float16)xs[2 * e], bb = (_Float16)xs[2 * e + 1];
        hw[e] = (unsigned int)h_bits(a) | ((unsigned int)h_bits(bb) << 16);
    }
    int r = b * T_DIM + t;            // batch-major row index
    *(uint4*)(Xh + tiled_idx(r, h0)) = make_uint4(hw[0], hw[1], hw[2], hw[3]);
}

// ---------- staging helpers: 1KB chunks of a pre-tiled 8KB subtile ----------
__device__ __forceinline__ void stage_half(const unsigned short* __restrict__ src_tile,
                                           unsigned short* lds_base, int lane, int h) {
#pragma unroll
    for (int c = 0; c < 4; ++c) {
        const int ch = h * 4 + c;
        __builtin_amdgcn_global_load_lds(
            (const __attribute__((address_space(1))) void*)(src_tile + ch * 512 + lane * 8),
            (__attribute__((address_space(3))) void*)(lds_base + ch * 512),
            16, 0, 0);
    }
}
__device__ __forceinline__ void stage_chunks(const unsigned short* __restrict__ src_tile,
                                             unsigned short* lds_base, int lane,
                                             int c0, int c1) {
    for (int c = c0; c < c1; ++c) {
        __builtin_amdgcn_global_load_lds(
            (const __attribute__((address_space(1))) void*)(src_tile + c * 512 + lane * 8),
            (__attribute__((address_space(3))) void*)(lds_base + c * 512),
            16, 0, 0);
    }
}

// ---------- Kernel 2: Q = X @ W, single-pass fp16 MFMA, BK=64 (R10-proven) ----------
__global__ __launch_bounds__(256) void k_qgemm_mfma(const unsigned short* __restrict__ Xh,
                                                    const unsigned short* __restrict__ Wth,
                                                    unsigned short* __restrict__ Qh) {
    __shared__ __align__(16) unsigned short Ah[2][4][128][8], Bh[2][4][128][8];
    const int bid = blockIdx.x;                       // 1024 = 8 * 128
    const int swz = (bid & 7) * 128 + (bid >> 3);     // bijective
    const int mblk = swz >> 2, nblk = swz & 3;
    const int m0 = mblk * 128, n0 = nblk * 128;
    const int tid = threadIdx.x, lane = tid & 63, w = tid >> 6;
    const int t_off = (w >> 1) * 64, s_off = (w & 1) * 64;
    const int l15 = lane & 15, lg = lane >> 4;
    f32x4 acc[4][4] = {};

    for (int ksp = 0; ksp < NKB / 2; ++ksp) {
        if (ksp) __syncthreads();
        if (w < 2) {
            stage_half(Xh + tile_off(mblk, 2 * ksp),     &Ah[0][0][0][0], lane, w);
            stage_half(Xh + tile_off(mblk, 2 * ksp + 1), &Ah[1][0][0][0], lane, w);
        } else {
            stage_half(Wth + tile_off(nblk, 2 * ksp),     &Bh[0][0][0][0], lane, w - 2);
            stage_half(Wth + tile_off(nblk, 2 * ksp + 1), &Bh[1][0][0][0], lane, w - 2);
        }
        __syncthreads();

#pragma unroll
        for (int kk = 0; kk < 2; ++kk) {
            f16x8 ah[4], bh[4];
#pragma unroll
            for (int i2 = 0; i2 < 4; ++i2)
                ah[i2] = *(const f16x8*)&Ah[kk][lg][t_off + i2 * 16 + l15][0];
#pragma unroll
            for (int j = 0; j < 4; ++j)
                bh[j] = *(const f16x8*)&Bh[kk][lg][s_off + j * 16 + l15][0];
#pragma unroll
            for (int i2 = 0; i2 < 4; ++i2)
#pragma unroll
                for (int j = 0; j < 4; ++j)
                    acc[i2][j] = __builtin_amdgcn_mfma_f32_16x16x32_f16(ah[i2], bh[j], acc[i2][j], 0, 0, 0);
        }
    }

#pragma unroll
    for (int i2 = 0; i2 < 4; ++i2)
#pragma unroll
        for (int j = 0; j < 4; ++j)
#pragma unroll
            for (int r = 0; r < 4; ++r) {
                int R = m0 + t_off + i2 * 16 + lg * 4 + r;
                int C = n0 + s_off + j * 16 + l15;
                _Float16 qh = (_Float16)acc[i2][j][r];
                Qh[tiled_idx(R, C)] = h_bits(qh);
            }
}

// ---------- Kernel 3: scores, 128x256 tile (A-reuse x2), fp16 raw output ----------
// Grid: 16 batches x 72 triangle (128-row x 256-col) tiles = 1152 = 8 * 144.
// Wave (wr,wc) owns 64 rows x 128 cols = 4x8 fragments. Dead half-tiles write
// garbage into the upper triangle, which k_softmax overwrites with zeros.
__global__ __launch_bounds__(256) void k_scores_mfma(const unsigned short* __restrict__ Qh,
                                                     const unsigned short* __restrict__ Xh,
                                                     float* __restrict__ attn) {
    const int bid = blockIdx.x;
    const int swz = (bid & 7) * 144 + (bid >> 3);     // bijective XCD chunking
    const int b = swz / 72;
    int r = swz - b * 72;
    int ti = 0;
    for (;; ++ti) {                                    // count(ti) = ceil((ti+1)/2)
        const int c = (ti + 2) >> 1;
        if (r < c) break;
        r -= c;
    }
    const int si2 = r;                                 // 256-col pair index, si2*2 <= ti
    const int t0 = ti * 128, s0 = si2 * 256;

    // subtiles: 0=A_k0 1=A_k1 2=B0_k0 3=B0_k1 4=B1_k0 5=B1_k1 (each 8KB, [g][row][8])
    __shared__ __align__(16) unsigned short S[6 * 4096];
    const int tid = threadIdx.x, lane = tid & 63, w = tid >> 6;
    const int wr = w >> 1, wc = w & 1;
    const int l15 = lane & 15, lg = lane >> 4;
    const int ablk  = b * (T_DIM / 128) + ti;
    const int bblk0 = b * (T_DIM / 128) + si2 * 2;
    f32x4 acc[4][8] = {};

    for (int ksp = 0; ksp < NKB / 2; ++ksp) {
        if (ksp) __syncthreads();
        {
            const unsigned short* A0  = Qh + tile_off(ablk, 2 * ksp);
            const unsigned short* A1  = Qh + tile_off(ablk, 2 * ksp + 1);
            const unsigned short* B00 = Xh + tile_off(bblk0, 2 * ksp);
            const unsigned short* B01 = Xh + tile_off(bblk0, 2 * ksp + 1);
            const unsigned short* B10 = Xh + tile_off(bblk0 + 1, 2 * ksp);
            const unsigned short* B11 = Xh + tile_off(bblk0 + 1, 2 * ksp + 1);
            if      (w == 0) { stage_chunks(A0,  S,            lane, 0, 8);
                               stage_chunks(A1,  S + 4096,     lane, 0, 4); }
            else if (w == 1) { stage_chunks(A1,  S + 4096,     lane, 4, 8);
                               stage_chunks(B00, S + 2 * 4096, lane, 0, 8); }
            else if (w == 2) { stage_chunks(B01, S + 3 * 4096, lane, 0, 8);
                               stage_chunks(B10, S + 4 * 4096, lane, 0, 4); }
            else             { stage_chunks(B10, S + 4 * 4096, lane, 4, 8);
                               stage_chunks(B11, S + 5 * 4096, lane, 0, 8); }
        }
        __syncthreads();

#pragma unroll
        for (int kk = 0; kk < 2; ++kk) {
            f16x8 ah[4], bh[8];
#pragma unroll
            for (int i2 = 0; i2 < 4; ++i2)
                ah[i2] = *(const f16x8*)&S[kk * 4096 + (lg * 128 + wr * 64 + i2 * 16 + l15) * 8];
#pragma unroll
            for (int j = 0; j < 8; ++j)
                bh[j] = *(const f16x8*)&S[(2 + wc * 2 + kk) * 4096 + (lg * 128 + j * 16 + l15) * 8];
#pragma unroll
            for (int i2 = 0; i2 < 4; ++i2)
#pragma unroll
                for (int j = 0; j < 8; ++j)
                    acc[i2][j] = __builtin_amdgcn_mfma_f32_16x16x32_f16(ah[i2], bh[j], acc[i2][j], 0, 0, 0);
        }
    }

    // raw fp16 scores into the row's low half (softmax masks/overwrites s >= t)
    float* base = attn + (size_t)b * T_DIM * T_DIM;
#pragma unroll
    for (int i2 = 0; i2 < 4; ++i2)
#pragma unroll
        for (int j = 0; j < 8; ++j)
#pragma unroll
            for (int rr = 0; rr < 4; ++rr) {
                int t = t0 + wr * 64 + i2 * 16 + lg * 4 + rr;
                int s = s0 + wc * 128 + j * 16 + l15;
                _Float16 hv = (_Float16)acc[i2][j][rr];
                ((unsigned short*)(base + (size_t)t * T_DIM))[s] = h_bits(hv);
            }
}

// ---------- Kernel 4: masked softmax; fp16-raw read (1 uint4/thread), f32 write ----------
__global__ __launch_bounds__(256) void k_softmax(float* __restrict__ attn) {
    const int row = blockIdx.x;
    const int t = row & (T_DIM - 1);
    float* p = attn + (size_t)row * T_DIM;
    const int tid = threadIdx.x;
    const int n = (t >= 2) ? t : 0;
    __shared__ float redm[4], redl[4];

    if (n == 0) {
        const float4 z = {0.f, 0.f, 0.f, 0.f};
        *(float4*)&p[tid * 8] = z;
        *(float4*)&p[tid * 8 + 4] = z;
        return;
    }

    const int sbase = tid * 8;
    uint4 rv = *(const uint4*)((const unsigned short*)p + sbase);
    float v[8];
    v[0] = h2f((unsigned short)(rv.x & 0xffff)); v[1] = h2f((unsigned short)(rv.x >> 16));
    v[2] = h2f((unsigned short)(rv.y & 0xffff)); v[3] = h2f((unsigned short)(rv.y >> 16));
    v[4] = h2f((unsigned short)(rv.z & 0xffff)); v[5] = h2f((unsigned short)(rv.z >> 16));
    v[6] = h2f((unsigned short)(rv.w & 0xffff)); v[7] = h2f((unsigned short)(rv.w >> 16));

    float m = -1e30f, l = 0.f;
#pragma unroll
    for (int j = 0; j < 8; ++j)
        if (sbase + j < n) m = fmaxf(m, v[j]);
#pragma unroll
    for (int j = 0; j < 8; ++j)
        if (sbase + j < n) l += expf(v[j] - m);

#pragma unroll
    for (int off = 1; off <= 32; off <<= 1) {
        float mo = __shfl_xor(m, off);
        float lo = __shfl_xor(l, off);
        float M = fmaxf(m, mo);
        l = l * expf(m - M) + lo * expf(mo - M);
        m = M;
    }
    if ((tid & 63) == 0) { redm[tid >> 6] = m; redl[tid >> 6] = l; }
    __syncthreads();   // fences raw-reads before f32 writes below
    {
        float M = fmaxf(fmaxf(redm[0], redm[1]), fmaxf(redm[2], redm[3]));
        float L = redl[0] * expf(redm[0] - M) + redl[1] * expf(redm[1] - M)
                + redl[2] * expf(redm[2] - M) + redl[3] * expf(redm[3] - M);
        m = M;
        l = L;
    }
    const float inv = 1.f / l;

    float o[8];
#pragma unroll
    for (int j = 0; j < 8; ++j)
        o[j] = (sbase + j < n) ? expf(v[j] - m) * inv : 0.f;
    float4 o0 = {o[0], o[1], o[2], o[3]};
    float4 o1 = {o[4], o[5], o[6], o[7]};
    *(float4*)&p[sbase] = o0;
    *(float4*)&p[sbase + 4] = o1;
}

extern "C" void kernel_launch(void* const* d_in, const int* in_sizes, int n_in,
                              void* d_out, int out_size, void* d_ws, size_t ws_size,
                              hipStream_t stream) {
    const float* inputs   = (const float*)d_in[0];   // [T,B,H]
    const float* rand_ctx = (const float*)d_in[1];   // [T,B,H]
    const float* W        = (const float*)d_in[2];   // [H,H]
    float* out  = (float*)d_out;
    float* attn = out + (size_t)T_DIM * B_DIM * 2 * H_DIM;

    unsigned short* Xh  = (unsigned short*)d_ws;
    unsigned short* Qh  = Xh + (size_t)33554432;
    unsigned short* Wth = Xh + (size_t)67108864;

    k_prep<<<dim3(8192 + 128), dim3(256), 0, stream>>>(
        inputs, rand_ctx, W, out, Xh, Wth);

    k_qgemm_mfma<<<dim3(1024), dim3(256), 0, stream>>>(Xh, Wth, Qh);

    k_scores_mfma<<<dim3(1152), dim3(256), 0, stream>>>(Qh, Xh, attn);

    k_softmax<<<dim3(B_DIM * T_DIM), dim3(256), 0, stream>>>(attn);
}

// Round 15
// 293.727 us; speedup vs baseline: 1.0827x; 1.0827x over previous
//
#include <hip/hip_runtime.h>
#include <math.h>

#define T_DIM 2048
#define B_DIM 16
#define H_DIM 512
#define NKB   (H_DIM / 32)   // 16 k-blocks of 32
// out: results [T,B,2H] (33,554,432 f32) then attn [B,T,T] (67,108,864 f32)
// ws (ushort = fp16 bits), arrays TILED: tile(rowblk,kblk) = 8KB as [g(4)][row(128)][8]
//   Xh @0 (32MB), Qh @32Mi elems (32MB), Wth @64Mi elems (512KB).
// Raw scores: fp16, packed into the LOW HALF of each attn row (bytes [0,4096) of
// the row's 8KB), overwritten in-place by k_softmax's f32 output.

typedef _Float16 f16x8 __attribute__((ext_vector_type(8)));
typedef float f32x4 __attribute__((ext_vector_type(4)));

__device__ __forceinline__ unsigned short h_bits(_Float16 h) {
    unsigned short u; __builtin_memcpy(&u, &h, 2); return u;
}
__device__ __forceinline__ float h2f(unsigned short u) {
    _Float16 h; __builtin_memcpy(&h, &u, 2); return (float)h;
}

__device__ __forceinline__ size_t tile_off(int rowblk, int kblk) {
    return ((size_t)rowblk * NKB + kblk) * 4096;   // 4096 ushorts = 8KB per tile
}
__device__ __forceinline__ size_t tiled_idx(int r, int c) {
    return tile_off(r >> 7, c >> 5) + (size_t)((c >> 3) & 3) * 1024 + (size_t)(r & 127) * 8 + (c & 7);
}

// ---------- Kernel 1: results copy + X -> fp16 (tiled) ; tail blocks: W transpose ----------
__global__ __launch_bounds__(256) void k_prep(const float* __restrict__ X,
                                              const float* __restrict__ RC,
                                              const float* __restrict__ W,
                                              float* __restrict__ out,
                                              unsigned short* __restrict__ Xh,
                                              unsigned short* __restrict__ Wth) {
    if (blockIdx.x >= 8192) {
        // ---- split_w part: 128 blocks, W -> transposed fp16, tiled [n][k] ----
        int i = (blockIdx.x - 8192) * 256 + threadIdx.x;
        int n = i & 511;
        int k0 = (i >> 9) * 8;
        unsigned int hw[4];
#pragma unroll
        for (int e = 0; e < 4; ++e) {
            _Float16 h0 = (_Float16)W[(size_t)(k0 + 2 * e) * H_DIM + n];
            _Float16 h1 = (_Float16)W[(size_t)(k0 + 2 * e + 1) * H_DIM + n];
            hw[e] = (unsigned int)h_bits(h0) | ((unsigned int)h_bits(h1) << 16);
        }
        *(uint4*)(Wth + tiled_idx(n, k0)) = make_uint4(hw[0], hw[1], hw[2], hw[3]);
        return;
    }
    int i = blockIdx.x * 256 + threadIdx.x;
    int row = i >> 6;                 // t*B + b
    int h0 = (i & 63) * 8;
    int t = row >> 4;
    int b = row & 15;
    const float* xp = X + (size_t)row * H_DIM + h0;
    float4 v0 = *(const float4*)xp;
    float4 v1 = *(const float4*)(xp + 4);
    float* op = out + (size_t)row * (2 * H_DIM) + h0;
    *(float4*)op = v0;
    *(float4*)(op + 4) = v1;
    const float* cp = RC + (size_t)row * H_DIM + h0;
    float4 c0 = *(const float4*)cp;
    float4 c1 = *(const float4*)(cp + 4);
    if (t < 2) { c0 = v0; c1 = v1; }
    *(float4*)(op + H_DIM) = c0;
    *(float4*)(op + H_DIM + 4) = c1;
    float xs[8] = {v0.x, v0.y, v0.z, v0.w, v1.x, v1.y, v1.z, v1.w};
    unsigned int hw[4];
#pragma unroll
    for (int e = 0; e < 4; ++e) {
        _Float16 a = (_Float16)xs[2 * e], bb = (_Float16)xs[2 * e + 1];
        hw[e] = (unsigned int)h_bits(a) | ((unsigned int)h_bits(bb) << 16);
    }
    int r = b * T_DIM + t;            // batch-major row index
    *(uint4*)(Xh + tiled_idx(r, h0)) = make_uint4(hw[0], hw[1], hw[2], hw[3]);
}

// ---------- staging: half of a pre-tiled 8KB tile -> LDS, linear coalesced copy ----------
__device__ __forceinline__ void stage_half(const unsigned short* __restrict__ src_tile,
                                           unsigned short* lds_base, int lane, int h) {
#pragma unroll
    for (int c = 0; c < 4; ++c) {
        const int ch = h * 4 + c;
        __builtin_amdgcn_global_load_lds(
            (const __attribute__((address_space(1))) void*)(src_tile + ch * 512 + lane * 8),
            (__attribute__((address_space(3))) void*)(lds_base + ch * 512),
            16, 0, 0);
    }
}

// ---------- Kernel 2: Q = X @ W, single-pass fp16 MFMA, BK=64 (R10-proven) ----------
__global__ __launch_bounds__(256) void k_qgemm_mfma(const unsigned short* __restrict__ Xh,
                                                    const unsigned short* __restrict__ Wth,
                                                    unsigned short* __restrict__ Qh) {
    __shared__ __align__(16) unsigned short Ah[2][4][128][8], Bh[2][4][128][8];
    const int bid = blockIdx.x;                       // 1024 = 8 * 128
    const int swz = (bid & 7) * 128 + (bid >> 3);     // bijective
    const int mblk = swz >> 2, nblk = swz & 3;
    const int m0 = mblk * 128, n0 = nblk * 128;
    const int tid = threadIdx.x, lane = tid & 63, w = tid >> 6;
    const int t_off = (w >> 1) * 64, s_off = (w & 1) * 64;
    const int l15 = lane & 15, lg = lane >> 4;
    f32x4 acc[4][4] = {};

    for (int ksp = 0; ksp < NKB / 2; ++ksp) {
        if (ksp) __syncthreads();
        if (w < 2) {
            stage_half(Xh + tile_off(mblk, 2 * ksp),     &Ah[0][0][0][0], lane, w);
            stage_half(Xh + tile_off(mblk, 2 * ksp + 1), &Ah[1][0][0][0], lane, w);
        } else {
            stage_half(Wth + tile_off(nblk, 2 * ksp),     &Bh[0][0][0][0], lane, w - 2);
            stage_half(Wth + tile_off(nblk, 2 * ksp + 1), &Bh[1][0][0][0], lane, w - 2);
        }
        __syncthreads();

#pragma unroll
        for (int kk = 0; kk < 2; ++kk) {
            f16x8 ah[4], bh[4];
#pragma unroll
            for (int i2 = 0; i2 < 4; ++i2)
                ah[i2] = *(const f16x8*)&Ah[kk][lg][t_off + i2 * 16 + l15][0];
#pragma unroll
            for (int j = 0; j < 4; ++j)
                bh[j] = *(const f16x8*)&Bh[kk][lg][s_off + j * 16 + l15][0];
#pragma unroll
            for (int i2 = 0; i2 < 4; ++i2)
#pragma unroll
                for (int j = 0; j < 4; ++j)
                    acc[i2][j] = __builtin_amdgcn_mfma_f32_16x16x32_f16(ah[i2], bh[j], acc[i2][j], 0, 0, 0);
        }
    }

    // scatter epilogue (proven pattern), hi-only fp16 output
#pragma unroll
    for (int i2 = 0; i2 < 4; ++i2)
#pragma unroll
        for (int j = 0; j < 4; ++j)
#pragma unroll
            for (int r = 0; r < 4; ++r) {
                int R = m0 + t_off + i2 * 16 + lg * 4 + r;
                int C = n0 + s_off + j * 16 + l15;
                _Float16 qh = (_Float16)acc[i2][j][r];
                Qh[tiled_idx(R, C)] = h_bits(qh);
            }
}

// ---------- Kernel 3: scores, single-pass fp16 MFMA; RAW fp16 into low half of row ----------
__global__ __launch_bounds__(256) void k_scores_mfma(const unsigned short* __restrict__ Qh,
                                                     const unsigned short* __restrict__ Xh,
                                                     float* __restrict__ attn) {
    // 2176 live blocks = 16 batches x 136 triangle tile-pairs; 2176 = 8 * 272
    const int bid = blockIdx.x;
    const int swz = (bid & 7) * 272 + (bid >> 3);     // bijective XCD chunking
    const int b = swz / 136;
    const int r = swz - b * 136;
    int ti = (int)((sqrtf(8.f * (float)r + 1.f) - 1.f) * 0.5f);
    while ((ti + 1) * (ti + 2) / 2 <= r) ++ti;
    while (ti * (ti + 1) / 2 > r) --ti;
    const int si = r - ti * (ti + 1) / 2;             // si <= ti
    const int t0 = ti * 128, s0 = si * 128;

    __shared__ __align__(16) unsigned short Ah[2][4][128][8], Bh[2][4][128][8];
    const int tid = threadIdx.x, lane = tid & 63, w = tid >> 6;
    const int t_off = (w >> 1) * 64, s_off = (w & 1) * 64;
    const int l15 = lane & 15, lg = lane >> 4;
    const int ablk = b * (T_DIM / 128) + ti;
    const int bblk = b * (T_DIM / 128) + si;
    f32x4 acc[4][4] = {};

    for (int ksp = 0; ksp < NKB / 2; ++ksp) {
        if (ksp) __syncthreads();
        if (w < 2) {
            stage_half(Qh + tile_off(ablk, 2 * ksp),     &Ah[0][0][0][0], lane, w);
            stage_half(Qh + tile_off(ablk, 2 * ksp + 1), &Ah[1][0][0][0], lane, w);
        } else {
            stage_half(Xh + tile_off(bblk, 2 * ksp),     &Bh[0][0][0][0], lane, w - 2);
            stage_half(Xh + tile_off(bblk, 2 * ksp + 1), &Bh[1][0][0][0], lane, w - 2);
        }
        __syncthreads();

#pragma unroll
        for (int kk = 0; kk < 2; ++kk) {
            f16x8 ah[4], bh[4];
#pragma unroll
            for (int i2 = 0; i2 < 4; ++i2)
                ah[i2] = *(const f16x8*)&Ah[kk][lg][t_off + i2 * 16 + l15][0];
#pragma unroll
            for (int j = 0; j < 4; ++j)
                bh[j] = *(const f16x8*)&Bh[kk][lg][s_off + j * 16 + l15][0];
#pragma unroll
            for (int i2 = 0; i2 < 4; ++i2)
#pragma unroll
                for (int j = 0; j < 4; ++j)
                    acc[i2][j] = __builtin_amdgcn_mfma_f32_16x16x32_f16(ah[i2], bh[j], acc[i2][j], 0, 0, 0);
        }
    }

    // raw scores as fp16 packed into the row's low half: ushort[s] at row base
    float* base = attn + (size_t)b * T_DIM * T_DIM;
#pragma unroll
    for (int i2 = 0; i2 < 4; ++i2)
#pragma unroll
        for (int j = 0; j < 4; ++j)
#pragma unroll
            for (int rr = 0; rr < 4; ++rr) {
                int t = t0 + t_off + i2 * 16 + lg * 4 + rr;
                int s = s0 + s_off + j * 16 + l15;
                _Float16 hv = (_Float16)acc[i2][j][rr];
                ((unsigned short*)(base + (size_t)t * T_DIM))[s] = h_bits(hv);
            }
}

// ---------- Kernel 4: masked softmax; fp16-raw read (1 uint4/thread), f32 write ----------
// 256 threads x 8 contiguous elems. All raw reads complete before the merge
// __syncthreads(); all f32 writes (which clobber the raw bytes) happen after.
__global__ __launch_bounds__(256) void k_softmax(float* __restrict__ attn) {
    const int row = blockIdx.x;
    const int t = row & (T_DIM - 1);
    float* p = attn + (size_t)row * T_DIM;
    const int tid = threadIdx.x;
    const int n = (t >= 2) ? t : 0;
    __shared__ float redm[4], redl[4];

    if (n == 0) {
        const float4 z = {0.f, 0.f, 0.f, 0.f};
        *(float4*)&p[tid * 8] = z;
        *(float4*)&p[tid * 8 + 4] = z;
        return;
    }

    // read this thread's 8 raw fp16 scores (coalesced uint4)
    const int sbase = tid * 8;
    uint4 rv = *(const uint4*)((const unsigned short*)p + sbase);
    float v[8];
    v[0] = h2f((unsigned short)(rv.x & 0xffff)); v[1] = h2f((unsigned short)(rv.x >> 16));
    v[2] = h2f((unsigned short)(rv.y & 0xffff)); v[3] = h2f((unsigned short)(rv.y >> 16));
    v[4] = h2f((unsigned short)(rv.z & 0xffff)); v[5] = h2f((unsigned short)(rv.z >> 16));
    v[6] = h2f((unsigned short)(rv.w & 0xffff)); v[7] = h2f((unsigned short)(rv.w >> 16));

    float m = -1e30f, l = 0.f;
#pragma unroll
    for (int j = 0; j < 8; ++j)
        if (sbase + j < n) m = fmaxf(m, v[j]);
#pragma unroll
    for (int j = 0; j < 8; ++j)
        if (sbase + j < n) l += expf(v[j] - m);

    // wave butterfly merge of (m, l)
#pragma unroll
    for (int off = 1; off <= 32; off <<= 1) {
        float mo = __shfl_xor(m, off);
        float lo = __shfl_xor(l, off);
        float M = fmaxf(m, mo);
        l = l * expf(m - M) + lo * expf(mo - M);
        m = M;
    }
    if ((tid & 63) == 0) { redm[tid >> 6] = m; redl[tid >> 6] = l; }
    __syncthreads();   // also fences raw-reads before f32 writes below
    {
        float M = fmaxf(fmaxf(redm[0], redm[1]), fmaxf(redm[2], redm[3]));
        float L = redl[0] * expf(redm[0] - M) + redl[1] * expf(redm[1] - M)
                + redl[2] * expf(redm[2] - M) + redl[3] * expf(redm[3] - M);
        m = M;
        l = L;
    }
    const float inv = 1.f / l;

    float o[8];
#pragma unroll
    for (int j = 0; j < 8; ++j)
        o[j] = (sbase + j < n) ? expf(v[j] - m) * inv : 0.f;
    float4 o0 = {o[0], o[1], o[2], o[3]};
    float4 o1 = {o[4], o[5], o[6], o[7]};
    *(float4*)&p[sbase] = o0;
    *(float4*)&p[sbase + 4] = o1;
}

extern "C" void kernel_launch(void* const* d_in, const int* in_sizes, int n_in,
                              void* d_out, int out_size, void* d_ws, size_t ws_size,
                              hipStream_t stream) {
    const float* inputs   = (const float*)d_in[0];   // [T,B,H]
    const float* rand_ctx = (const float*)d_in[1];   // [T,B,H]
    const float* W        = (const float*)d_in[2];   // [H,H]
    float* out  = (float*)d_out;
    float* attn = out + (size_t)T_DIM * B_DIM * 2 * H_DIM;

    unsigned short* Xh  = (unsigned short*)d_ws;
    unsigned short* Qh  = Xh + (size_t)33554432;
    unsigned short* Wth = Xh + (size_t)67108864;

    // prep (8192 blocks) + W transpose (128 tail blocks) in one dispatch
    k_prep<<<dim3(8192 + 128), dim3(256), 0, stream>>>(
        inputs, rand_ctx, W, out, Xh, Wth);

    k_qgemm_mfma<<<dim3(1024), dim3(256), 0, stream>>>(Xh, Wth, Qh);

    k_scores_mfma<<<dim3(2176), dim3(256), 0, stream>>>(Qh, Xh, attn);

    k_softmax<<<dim3(B_DIM * T_DIM), dim3(256), 0, stream>>>(attn);
}